// Round 1
// 296.760 us; speedup vs baseline: 1.0262x; 1.0262x over previous
//
#include <hip/hip_runtime.h>
#include <math.h>

// ---------------------------------------------------------------------------
// RTF-SSM block, MI355X. FFT path replaced by:
//   K = impulse response of B(z)/A(z), truncated at 512 taps (Newton
//   power-series inversion, 9 wave-parallel doubling steps).
//   causal conv = Toeplitz-block bf16 MFMA (16x16x32), A-frags prebuilt.
//   3 GEMMs (65536x256x256) bf16 MFMA with fused bias/gelu/skip/LN/max.
// R5: k_conv restructured: t-tile 2048 (halo redundancy 3.1x -> 1.27x),
//   wave-owns-channel with 17 A-frags held in VGPRs, xe staged via
//   global_load_lds w/ XOR-perm as per-lane global offsets, 2 barriers/block.
// R6: VALU diet (k_conv was VALUBusy 50% / Mfma 11%):
//   - gelu: erff (~30 v-ops) -> tanh-form x*sigmoid(2y) via v_exp_f32 +
//     v_rcp_f32 (8 ops, max |err| ~2e-4, << bf16 noise). Also in k_gemm2
//     (64 gelus/thread there).
//   - k_conv: 17 swizzled LDS addresses live in VGPRs and SLIDE across
//     s-steps: ad(s+1,dd)=ad(s,dd-8) (rotate), ad(s+1,dd<8)=(ad+512)^64
//     (+32 chunks flips bit2 of XOR mask = byte bit 6). Zero per-MFMA
//     address math.
//   - k_conv epilogue: h0*xe term read as one ds_read_b64 (4 r's share an
//     8B half-chunk) with its own sliding address, was 4x ds_read_u16.
// ---------------------------------------------------------------------------

#define BSZ   8
#define SEQ   8192
#define CHN   256
#define ORD   64
#define STAPS 512
#define NDD   17            // d-pairs: covers d = 0..33 (taps to 543 >= 511)
#define PREPAD 544          // history prepad (>= 528 needed), 16-aligned
#define XROW  (PREPAD + SEQ) // 8736 elems per (b,c) row of xe^T
#define MTOT  (BSZ * SEQ)   // 65536
#define YELEMS (MTOT * CHN) // 16777216

#define CT     2048         // conv t-tile per block
#define CROWE  3072         // conv LDS row stride (384 chunks)

typedef short s16x8 __attribute__((ext_vector_type(8)));
typedef float f32x4 __attribute__((ext_vector_type(4)));

#define MFMA16(a, b, c) __builtin_amdgcn_mfma_f32_16x16x32_bf16((a), (b), (c), 0, 0, 0)

// async global->LDS 16B: LDS dest = wave-uniform base + lane*16
__device__ __forceinline__ void gll16(const void* g, void* l) {
  __builtin_amdgcn_global_load_lds(
      (const __attribute__((address_space(1))) unsigned int*)g,
      (__attribute__((address_space(3))) unsigned int*)l, 16, 0, 0);
}

// XOR-perm chunk layout: chunk p of (row,h) stored at elems PERMC
#define PERMC(row, h) (((row) * 8 + ((h) ^ ((row) & 7))) * 8)

__device__ __forceinline__ unsigned short f2bf(float f) {
  unsigned u = __float_as_uint(f);
  return (unsigned short)((u + 0x7FFFu + ((u >> 16) & 1u)) >> 16);
}
__device__ __forceinline__ float bf2f(unsigned short h) {
  return __uint_as_float(((unsigned)h) << 16);
}
// tanh-form gelu: x * sigmoid(2*sqrt(2/pi)*(x + 0.044715 x^3)).
// 8 VALU ops (v_exp_f32 + v_rcp_f32). |err| vs exact erf-gelu < ~2e-4.
// Large -x: exp2 -> inf -> rcp -> 0 -> result 0 (correct limit).
__device__ __forceinline__ float geluf(float x) {
  float x2 = x * x;
  float y = x * __builtin_fmaf(0.0356774081f, x2, 0.7978845608f);
  float e = __builtin_amdgcn_exp2f(-2.8853900818f * y);  // exp(-2y)
  return x * __builtin_amdgcn_rcpf(1.0f + e);
}
__device__ __forceinline__ uint4 packbf8(float4 a, float4 b) {
  uint4 r;
  r.x = (unsigned)f2bf(a.x) | ((unsigned)f2bf(a.y) << 16);
  r.y = (unsigned)f2bf(a.z) | ((unsigned)f2bf(a.w) << 16);
  r.z = (unsigned)f2bf(b.x) | ((unsigned)f2bf(b.y) << 16);
  r.w = (unsigned)f2bf(b.z) | ((unsigned)f2bf(b.w) << 16);
  return r;
}

// ---------------------------------------------------------------- weights->bf16
__global__ __launch_bounds__(256) void k_prep(const float* we, const float* wf,
                                              const float* wd, unsigned short* owe,
                                              unsigned short* owf, unsigned short* owd) {
  int i = blockIdx.x * 256 + threadIdx.x;       // grid 768 -> 196608
  int which = i >> 16, off = i & 65535;
  if (which == 0)      owe[off] = f2bf(we[off]);
  else if (which == 1) owf[off] = f2bf(wf[off]);
  else                 owd[off] = f2bf(wd[off]);
}

// ------------------------------------------------- zero prepads + max buffers
__global__ __launch_bounds__(256) void k_zero(unsigned short* xeT, uint4* maxbufs) {
  int i = blockIdx.x * 256 + threadIdx.x;       // grid 548
  uint4 z; z.x = 0; z.y = 0; z.z = 0; z.w = 0;
  if (i < 2048 * 68) {                          // 544 elems/row = 68 x 16B chunks
    int row = i / 68, cc = i % 68;
    *(uint4*)((char*)xeT + (size_t)row * (XROW * 2) + (size_t)cc * 16) = z;
  } else {
    int j = i - 2048 * 68;
    if (j < 1024) maxbufs[j] = z;               // maxxe (8KB) + maxy (8KB)
  }
}

// ---------------- K-gen: Newton inversion of A(z) + B*G conv + Toeplitz frags
__global__ __launch_bounds__(256) void k_kgen(const float* A, const float* Bp,
                                              unsigned short* afr) {
  __shared__ float Gs[4][STAPS];
  __shared__ float Et[4][64];
  __shared__ float Ac[4][65];
  __shared__ float Bb[4][64];
  __shared__ float Kb[4][STAPS];
  int lane = threadIdx.x & 63, wv = threadIdx.x >> 6;
  int c = blockIdx.x * 4 + wv;                  // grid 64
  Ac[wv][lane + 1] = A[(size_t)c * ORD + lane];
  Bb[wv][lane]     = Bp[(size_t)c * ORD + lane];
  if (lane == 0) { Ac[wv][0] = 1.f; Gs[wv][0] = 1.f; }
  __syncthreads();

  for (int n = 1; n < STAPS; n <<= 1) {
    float e = 0.f;
    int uhi = min(n + lane, 64);
    for (int u = lane + 1; u <= uhi; ++u)
      e += Ac[wv][u] * Gs[wv][n + lane - u];
    Et[wv][lane] = e;
    __syncthreads();
    int nk = (n + 63) >> 6;
    for (int k = 0; k < nk; ++k) {
      int idx = k * 64 + lane;
      if (idx < n) {
        float acc = 0.f;
        int imax = min(idx, 63);
        for (int i = 0; i <= imax; ++i)
          acc += Et[wv][i] * Gs[wv][idx - i];
        Gs[wv][n + idx] = -acc;
      }
    }
    __syncthreads();
  }

  for (int k = 0; k < 8; ++k) {
    int t = k * 64 + lane;
    float acc = 0.f;
    int jmax = min(t, 63);
    for (int j = 0; j <= jmax; ++j)
      acc += Bb[wv][j] * Gs[wv][t - j];
    Kb[wv][t] = acc;
  }
  __syncthreads();

  int m = lane & 15, quad = lane >> 4;
  for (int dd = 0; dd < NDD; ++dd) {
    unsigned short v[8];
#pragma unroll
    for (int j = 0; j < 8; ++j) {
      int k = quad * 8 + j;
      int d = 2 * dd + (k >> 4);
      int p = k & 15;
      int s = 16 * d + m - p;
      float kv = (s >= 0 && s < STAPS) ? Kb[wv][s] : 0.f;
      v[j] = f2bf(kv);
    }
    uint4 pk;
    pk.x = (unsigned)v[0] | ((unsigned)v[1] << 16);
    pk.y = (unsigned)v[2] | ((unsigned)v[3] << 16);
    pk.z = (unsigned)v[4] | ((unsigned)v[5] << 16);
    pk.w = (unsigned)v[6] | ((unsigned)v[7] << 16);
    *(uint4*)(afr + ((size_t)(c * NDD + dd) * 64 + lane) * 8) = pk;
  }
}

// --------------- GEMM1 (transposed out): xe^T[cout][t] = W_enc x^T + b_enc
// block: 256 cout x 64 t; BK=64; W via global_load_lds, x converted in VGPRs
__global__ __launch_bounds__(256) void k_gemm1(const float* x, const unsigned short* wb,
                                               const float* benc, unsigned short* xeT,
                                               unsigned int* maxxe) {
  __shared__ __align__(16) unsigned short As[256 * 64]; // W tile, perm layout
  __shared__ __align__(16) unsigned short Bs[64 * 64];  // x tile, perm layout
  int tid = threadIdx.x, lane = tid & 63, wv = tid >> 6;
  int ln15 = lane & 15, hf = lane >> 4;
  size_t t0 = (size_t)blockIdx.x * 64;          // grid 1024
  int b = (int)(t0 >> 13), tin = (int)(t0 & 8191);
  f32x4 acc[4][4];
#pragma unroll
  for (int i = 0; i < 4; ++i)
#pragma unroll
    for (int j = 0; j < 4; ++j) { acc[i][j][0]=0.f; acc[i][j][1]=0.f; acc[i][j][2]=0.f; acc[i][j][3]=0.f; }

  for (int k0 = 0; k0 < CHN; k0 += 64) {
    __syncthreads();
#pragma unroll
    for (int i = 0; i < 8; ++i) {
      int p = 512 * wv + 64 * i + lane;
      int row = p >> 3, h = (p & 7) ^ (row & 7);
      gll16(wb + (size_t)row * CHN + k0 + h * 8, &As[(512 * wv + 64 * i) * 8]);
    }
    {  // x: 64x64 fp32->bf16, 2 chunks/thread
      int row = tid >> 2, hb = (tid & 3) * 2;
      const float* src = x + (t0 + row) * CHN + k0 + hb * 8;
      float4 f0 = *(const float4*)src;
      float4 f1 = *(const float4*)(src + 4);
      float4 f2 = *(const float4*)(src + 8);
      float4 f3 = *(const float4*)(src + 12);
      *(uint4*)&Bs[PERMC(row, hb)]     = packbf8(f0, f1);
      *(uint4*)&Bs[PERMC(row, hb + 1)] = packbf8(f2, f3);
    }
    __syncthreads();
#pragma unroll
    for (int ks = 0; ks < 2; ++ks) {
      s16x8 af[4], bfr[4];
#pragma unroll
      for (int mt = 0; mt < 4; ++mt) {
        int row = 64 * wv + 16 * mt + ln15;
        af[mt] = *(const s16x8*)&As[PERMC(row, ks * 4 + hf)];
      }
#pragma unroll
      for (int nt = 0; nt < 4; ++nt) {
        int row = 16 * nt + ln15;
        bfr[nt] = *(const s16x8*)&Bs[PERMC(row, ks * 4 + hf)];
      }
#pragma unroll
      for (int mt = 0; mt < 4; ++mt)
#pragma unroll
        for (int nt = 0; nt < 4; ++nt)
          acc[mt][nt] = MFMA16(af[mt], bfr[nt], acc[mt][nt]);
    }
  }
  // epilogue: D[m=cout][n=t]; col=lane&15=t, row=quad*4+r
  int quad = hf;
#pragma unroll
  for (int mt = 0; mt < 4; ++mt) {
#pragma unroll
    for (int r = 0; r < 4; ++r) {
      int row = 64 * wv + 16 * mt + 4 * quad + r;
      float bias = benc[row];
      float mv = 0.f;
#pragma unroll
      for (int nt = 0; nt < 4; ++nt) {
        float v = acc[mt][nt][r] + bias;
        int t = tin + 16 * nt + ln15;
        xeT[(size_t)(b * CHN + row) * XROW + PREPAD + t] = f2bf(v);
        mv = fmaxf(mv, fabsf(v));
      }
      mv = fmaxf(mv, __shfl_xor(mv, 1)); mv = fmaxf(mv, __shfl_xor(mv, 2));
      mv = fmaxf(mv, __shfl_xor(mv, 4)); mv = fmaxf(mv, __shfl_xor(mv, 8));
      if (ln15 == 0) atomicMax(&maxxe[b * CHN + row], __float_as_uint(mv));
    }
  }
}

// ------------- conv: y1[t][c] = gelu(FIR(xe) + h0*xe)
// block = 4 ch x 2048 t; wave owns 1 channel; A-frags in VGPRs.
// R6: swizzled LDS addresses slide in registers (rotate-8 + (a+512)^64).
__global__ __launch_bounds__(256) void k_conv(const unsigned short* xeT,
                                              const unsigned short* afr,
                                              unsigned short* y1, const float* h0p) {
  __shared__ __align__(16) unsigned short xet[4 * CROWE]; // 4 rows x 384 chunks
  __shared__ __align__(16) unsigned short bnc[4 * CT];    // transpose bounce
  int tid = threadIdx.x, lane = tid & 63, wv = tid >> 6;
  int idx = blockIdx.x;                          // grid 2048 = 8b x 64cg x 4tg
  int tg = idx & 3, cg = (idx >> 2) & 63, b = idx >> 8;
  int c0 = cg * 4, t0 = tg * CT;
  int c = c0 + wv;

  // a-frags into registers (17 x 16B coalesced loads)
  s16x8 afrg[NDD];
  {
    const unsigned short* ap = afr + (size_t)c * (NDD * 512) + (size_t)lane * 8;
#pragma unroll
    for (int dd = 0; dd < NDD; ++dd)
      afrg[dd] = *(const s16x8*)(ap + (size_t)dd * 512);
  }
  // stage own channel's row [t0-544, t0+2048+..) via global_load_lds;
  // LDS slot s holds global chunk s^((s>>3)&7) (involution), so read-side
  // swizzle sw = cc^((cc>>3)&7) finds chunk cc.
  {
    int lp = lane ^ ((lane >> 3) & 7);
    const unsigned short* gbase = xeT + (size_t)(b * CHN + c) * XROW + t0;
    unsigned short* lbase = &xet[wv * CROWE];
#pragma unroll
    for (int k = 0; k < 6; ++k)
      gll16(gbase + (size_t)(64 * k + lp) * 8, &lbase[k * 64 * 8]);
  }
  float h0 = h0p[0];

  int n = lane & 15, quad = lane >> 4;
  int qc = quad - ((quad >> 1) << 2);            // 0,1,-2,-1
  const char* xb = (const char*)&xet[wv * CROWE];

  // sliding swizzled byte addresses: ad[dd](s) = sw(cb0 + 32s - 4dd)*16.
  // Slide: ad(s+1,dd>=8) = ad(s,dd-8); ad(s+1,dd<8) = (ad(s,dd)+512)^64.
  int ad[NDD];
  {
    int cb0 = 2 * n + qc + 68;
#pragma unroll
    for (int dd = 0; dd < NDD; ++dd) {
      int cc = cb0 - 4 * dd;
      ad[dd] = (cc ^ ((cc >> 3) & 7)) * 16;
    }
  }
  // epilogue xv address: chunk 68 + 2n + (quad>>1), byte off 8*(quad&1)
  int ead;
  {
    int ch = 68 + 2 * n + (quad >> 1);
    ead = (ch ^ ((ch >> 3) & 7)) * 16 + 8 * (quad & 1);
  }
  __syncthreads();

#pragma unroll 1
  for (int s = 0; s < 8; ++s) {
    f32x4 a0, a1;
    a0[0]=0.f; a0[1]=0.f; a0[2]=0.f; a0[3]=0.f;
    a1[0]=0.f; a1[1]=0.f; a1[2]=0.f; a1[3]=0.f;
#pragma unroll
    for (int dd = 0; dd < 16; dd += 2) {
      a0 = MFMA16(afrg[dd],     *(const s16x8*)(xb + ad[dd]),     a0);
      a1 = MFMA16(afrg[dd + 1], *(const s16x8*)(xb + ad[dd + 1]), a1);
    }
    a0 = MFMA16(afrg[16], *(const s16x8*)(xb + ad[16]), a0);
    // epilogue: tl = 256s + 16n + 4q + r; xv for 4 r's = one b64 read
    uint2 xvp = *(const uint2*)(xb + ead);
    unsigned short o[4];
#pragma unroll
    for (int r = 0; r < 4; ++r) {
      float xv = bf2f(((const unsigned short*)&xvp)[r]);
      float v = (a0[r] + a1[r]) + h0 * xv;
      o[r] = f2bf(geluf(v));
    }
    uint2 pw;
    pw.x = (unsigned)o[0] | ((unsigned)o[1] << 16);
    pw.y = (unsigned)o[2] | ((unsigned)o[3] << 16);
    *(uint2*)&bnc[wv * CT + 256 * s + 16 * n + 4 * quad] = pw;
    // slide addresses to s+1 (rotate high<-low, then bump low 8)
#pragma unroll
    for (int dd = 16; dd >= 8; --dd) ad[dd] = ad[dd - 8];
#pragma unroll
    for (int dd = 0; dd < 8; ++dd) ad[dd] = (ad[dd] + 512) ^ 64;
    ead = (ead + 512) ^ 64;
  }
  __syncthreads();
  // store: 4 ch per t as uint2, 8 rounds
  {
    const size_t obase = (size_t)(b * SEQ + t0) * CHN + c0;
#pragma unroll
    for (int s = 0; s < 8; ++s) {
      int tl = 256 * s + tid;
      uint2 pk;
      pk.x = (unsigned)bnc[tl] | ((unsigned)bnc[CT + tl] << 16);
      pk.y = (unsigned)bnc[2 * CT + tl] | ((unsigned)bnc[3 * CT + tl] << 16);
      *(uint2*)(y1 + obase + (size_t)tl * CHN) = pk;
    }
  }
}

// ------ GEMM2: y2n = LN(gelu(y1 W_fc^T + b_fc) + xe)*gamma+beta, in-place y1
// block: 64 t x 256 cout; BK=64; full global_load_lds staging
__global__ __launch_bounds__(256) void k_gemm2(const unsigned short* y1,
                                               const unsigned short* wb, const float* bfc,
                                               const unsigned short* xeT, const float* gam,
                                               const float* bet, unsigned short* y2n) {
  __shared__ __align__(16) unsigned short Ws[256 * 64];
  __shared__ __align__(16) unsigned short Asb[64 * 64];
  __shared__ float pl[64][2][2];
  int tid = threadIdx.x, lane = tid & 63, wv = tid >> 6;
  int ln15 = lane & 15, hf = lane >> 4, quad = hf;
  size_t M0 = (size_t)blockIdx.x * 64;           // grid 1024
  int b = (int)(M0 >> 13), tin = (int)(M0 & 8191);
  int mh = wv & 1, nh = wv >> 1;
  f32x4 acc[2][8];
#pragma unroll
  for (int i = 0; i < 2; ++i)
#pragma unroll
    for (int j = 0; j < 8; ++j) { acc[i][j][0]=0.f; acc[i][j][1]=0.f; acc[i][j][2]=0.f; acc[i][j][3]=0.f; }

  for (int k0 = 0; k0 < CHN; k0 += 64) {
    __syncthreads();
#pragma unroll
    for (int i = 0; i < 8; ++i) {               // W: 2048 chunks
      int p = 512 * wv + 64 * i + lane;
      int row = p >> 3, h = (p & 7) ^ (row & 7);
      gll16(wb + (size_t)row * CHN + k0 + h * 8, &Ws[(512 * wv + 64 * i) * 8]);
    }
#pragma unroll
    for (int i = 0; i < 2; ++i) {               // A: 512 chunks
      int p = 128 * wv + 64 * i + lane;
      int row = p >> 3, h = (p & 7) ^ (row & 7);
      gll16(y1 + (M0 + row) * CHN + k0 + h * 8, &Asb[(128 * wv + 64 * i) * 8]);
    }
    __syncthreads();
#pragma unroll
    for (int ks = 0; ks < 2; ++ks) {
      s16x8 af[2], bfr[8];
#pragma unroll
      for (int mt = 0; mt < 2; ++mt) {
        int row = 32 * mh + 16 * mt + ln15;
        af[mt] = *(const s16x8*)&Asb[PERMC(row, ks * 4 + hf)];
      }
#pragma unroll
      for (int nt = 0; nt < 8; ++nt) {
        int row = 128 * nh + 16 * nt + ln15;
        bfr[nt] = *(const s16x8*)&Ws[PERMC(row, ks * 4 + hf)];
      }
#pragma unroll
      for (int mt = 0; mt < 2; ++mt)
#pragma unroll
        for (int nt = 0; nt < 8; ++nt)
          acc[mt][nt] = MFMA16(af[mt], bfr[nt], acc[mt][nt]);
    }
  }
  float g8[8], be8[8], bf8[8];
#pragma unroll
  for (int nt = 0; nt < 8; ++nt) {
    int col = 128 * nh + 16 * nt + ln15;
    g8[nt] = gam[col]; be8[nt] = bet[col]; bf8[nt] = bfc[col];
  }
#pragma unroll
  for (int mt = 0; mt < 2; ++mt) {
    int mlb = 32 * mh + 16 * mt + 4 * quad;
    uint2 xv2[8];
#pragma unroll
    for (int nt = 0; nt < 8; ++nt) {            // xe skip: 4 consecutive t per lane
      int col = 128 * nh + 16 * nt + ln15;
      xv2[nt] = *(const uint2*)(xeT + (size_t)(b * CHN + col) * XROW + PREPAD + tin + mlb);
    }
#pragma unroll
    for (int r = 0; r < 4; ++r) {
      int ml = mlb + r;
      float s1 = 0.f, s2 = 0.f;
#pragma unroll
      for (int nt = 0; nt < 8; ++nt) {
        float t2 = acc[mt][nt][r] + bf8[nt];
        float xv = bf2f(((const unsigned short*)&xv2[nt])[r]);
        float y2 = geluf(t2) + xv;
        acc[mt][nt][r] = y2;
        s1 += y2; s2 += y2 * y2;
      }
      s1 += __shfl_xor(s1, 1); s2 += __shfl_xor(s2, 1);
      s1 += __shfl_xor(s1, 2); s2 += __shfl_xor(s2, 2);
      s1 += __shfl_xor(s1, 4); s2 += __shfl_xor(s2, 4);
      s1 += __shfl_xor(s1, 8); s2 += __shfl_xor(s2, 8);
      if (ln15 == 0) { pl[ml][nh][0] = s1; pl[ml][nh][1] = s2; }
    }
  }
  __syncthreads();
#pragma unroll
  for (int mt = 0; mt < 2; ++mt) {
#pragma unroll
    for (int r = 0; r < 4; ++r) {
      int ml = 32 * mh + 16 * mt + 4 * quad + r;
      float s1 = pl[ml][0][0] + pl[ml][1][0];
      float s2 = pl[ml][0][1] + pl[ml][1][1];
      float mu = s1 * (1.f / 256.f);
      float var = s2 * (1.f / 256.f) - mu * mu;
      float ri = rsqrtf(var + 1e-5f);
#pragma unroll
      for (int nt = 0; nt < 8; ++nt) {
        int col = 128 * nh + 16 * nt + ln15;
        float yn = (acc[mt][nt][r] - mu) * ri * g8[nt] + be8[nt];
        y2n[(M0 + ml) * CHN + col] = f2bf(yn);
      }
    }
  }
}

// ------------------- GEMM3: y = y2n W_dec^T + b_dec (fp32 out) + maxy atomics
__global__ __launch_bounds__(256) void k_gemm3(const unsigned short* y2n,
                                               const unsigned short* wb, const float* bd,
                                               float* yout, unsigned int* maxy) {
  __shared__ __align__(16) unsigned short Ws[256 * 64];
  __shared__ __align__(16) unsigned short Asb[64 * 64];
  int tid = threadIdx.x, lane = tid & 63, wv = tid >> 6;
  int ln15 = lane & 15, hf = lane >> 4, quad = hf;
  size_t M0 = (size_t)blockIdx.x * 64;           // grid 1024
  int b = (int)(M0 >> 13);
  int mh = wv & 1, nh = wv >> 1;
  f32x4 acc[2][8];
#pragma unroll
  for (int i = 0; i < 2; ++i)
#pragma unroll
    for (int j = 0; j < 8; ++j) { acc[i][j][0]=0.f; acc[i][j][1]=0.f; acc[i][j][2]=0.f; acc[i][j][3]=0.f; }

  for (int k0 = 0; k0 < CHN; k0 += 64) {
    __syncthreads();
#pragma unroll
    for (int i = 0; i < 8; ++i) {               // W: 2048 chunks
      int p = 512 * wv + 64 * i + lane;
      int row = p >> 3, h = (p & 7) ^ (row & 7);
      gll16(wb + (size_t)row * CHN + k0 + h * 8, &Ws[(512 * wv + 64 * i) * 8]);
    }
#pragma unroll
    for (int i = 0; i < 2; ++i) {               // A: 512 chunks
      int p = 128 * wv + 64 * i + lane;
      int row = p >> 3, h = (p & 7) ^ (row & 7);
      gll16(y2n + (M0 + row) * CHN + k0 + h * 8, &Asb[(128 * wv + 64 * i) * 8]);
    }
    __syncthreads();
#pragma unroll
    for (int ks = 0; ks < 2; ++ks) {
      s16x8 af[2], bfr[8];
#pragma unroll
      for (int mt = 0; mt < 2; ++mt) {
        int row = 32 * mh + 16 * mt + ln15;
        af[mt] = *(const s16x8*)&Asb[PERMC(row, ks * 4 + hf)];
      }
#pragma unroll
      for (int nt = 0; nt < 8; ++nt) {
        int row = 128 * nh + 16 * nt + ln15;
        bfr[nt] = *(const s16x8*)&Ws[PERMC(row, ks * 4 + hf)];
      }
#pragma unroll
      for (int mt = 0; mt < 2; ++mt)
#pragma unroll
        for (int nt = 0; nt < 8; ++nt)
          acc[mt][nt] = MFMA16(af[mt], bfr[nt], acc[mt][nt]);
    }
  }
  float bd8[8];
#pragma unroll
  for (int nt = 0; nt < 8; ++nt) bd8[nt] = bd[128 * nh + 16 * nt + ln15];
#pragma unroll
  for (int mt = 0; mt < 2; ++mt)
#pragma unroll
    for (int r = 0; r < 4; ++r) {
      int ml = 32 * mh + 16 * mt + 4 * quad + r;
#pragma unroll
      for (int nt = 0; nt < 8; ++nt) {
        int col = 128 * nh + 16 * nt + ln15;
        float v = acc[mt][nt][r] + bd8[nt];
        acc[mt][nt][r] = v;
        yout[(M0 + ml) * CHN + col] = v;
      }
    }
#pragma unroll
  for (int nt = 0; nt < 8; ++nt) {
    int col = 128 * nh + 16 * nt + ln15;
    float mv = 0.f;
#pragma unroll
    for (int mt = 0; mt < 2; ++mt)
#pragma unroll
      for (int r = 0; r < 4; ++r) mv = fmaxf(mv, fabsf(acc[mt][nt][r]));
    mv = fmaxf(mv, __shfl_xor(mv, 16));
    mv = fmaxf(mv, __shfl_xor(mv, 32));
    if (quad == 0) atomicMax(&maxy[b * CHN + col], __float_as_uint(mv));
  }
}

// ------------------------------------------------------------ h = my/(mx+eps)
__global__ __launch_bounds__(256) void k_hfin(const unsigned int* maxxe,
                                              const unsigned int* maxy, float* hout) {
  int i = blockIdx.x * 256 + threadIdx.x;        // grid 8
  if (i < BSZ * CHN) {
    float mx = __uint_as_float(maxxe[i]);
    float my = __uint_as_float(maxy[i]);
    hout[i] = my / (mx + 1e-6f);
  }
}

// ---------------------------------------------------------------------------
extern "C" void kernel_launch(void* const* d_in, const int* in_sizes, int n_in,
                              void* d_out, int out_size, void* d_ws, size_t ws_size,
                              hipStream_t stream) {
  const float* x   = (const float*)d_in[0];
  const float* A   = (const float*)d_in[1];
  const float* Bp  = (const float*)d_in[2];
  const float* h0  = (const float*)d_in[3];
  const float* We  = (const float*)d_in[4];
  const float* be  = (const float*)d_in[5];
  const float* Wf  = (const float*)d_in[6];
  const float* bfc = (const float*)d_in[7];
  const float* gam = (const float*)d_in[8];
  const float* bet = (const float*)d_in[9];
  const float* Wd  = (const float*)d_in[10];
  const float* bd  = (const float*)d_in[11];

  char* ws = (char*)d_ws;
  unsigned short* y1  = (unsigned short*)(ws + 0);          // 33554432 B
  unsigned short* afr = (unsigned short*)(ws + 33554432);   //  4456448 B
  unsigned short* web = (unsigned short*)(ws + 38010880);   //   131072 B
  unsigned short* wfb = (unsigned short*)(ws + 38141952);
  unsigned short* wdb = (unsigned short*)(ws + 38273024);
  unsigned int*  maxxe = (unsigned int*)(ws + 38404096);    //     8192 B
  unsigned int*  maxy  = (unsigned int*)(ws + 38412288);    //     8192 B

  unsigned short* xeT = (unsigned short*)d_out;             // scratch: 35.8 MB
  float* yout = (float*)d_out;
  float* hout = yout + YELEMS;

  k_prep<<<768, 256, 0, stream>>>(We, Wf, Wd, web, wfb, wdb);
  k_zero<<<548, 256, 0, stream>>>(xeT, (uint4*)maxxe);
  k_kgen<<<64, 256, 0, stream>>>(A, Bp, afr);
  k_gemm1<<<1024, 256, 0, stream>>>(x, web, be, xeT, maxxe);
  k_conv<<<2048, 256, 0, stream>>>(xeT, afr, y1, h0);
  k_gemm2<<<1024, 256, 0, stream>>>(y1, wfb, bfc, xeT, gam, bet, y1);
  k_gemm3<<<1024, 256, 0, stream>>>(y1, wdb, bd, yout, maxy);
  k_hfin<<<8, 256, 0, stream>>>(maxxe, maxy, hout);
}

// Round 2
// 279.611 us; speedup vs baseline: 1.0891x; 1.0613x over previous
//
#include <hip/hip_runtime.h>
#include <math.h>

// ---------------------------------------------------------------------------
// RTF-SSM block, MI355X. FFT path replaced by:
//   K = impulse response of B(z)/A(z), truncated at 512 taps (Newton
//   power-series inversion, 9 wave-parallel doubling steps).
//   causal conv = Toeplitz-block bf16 MFMA (16x16x32), A-frags prebuilt.
//   3 GEMMs (65536x256x256) bf16 MFMA with fused bias/gelu/skip/LN/max.
// R6: VALU diet in k_conv (gelu via exp2+rcp, sliding swizzled LDS addrs).
// R7: k_kgen was the hidden #1 (63us, VALUBusy 2%, occupancy 2.7% -- pure
//   exposed LDS latency from runtime-bound inner loops):
//   - zero-padded G array (64 leading zeros + pre-zeroed tail) makes every
//     inner loop a FIXED 64 iterations (out-of-range terms multiply exact
//     zeros) -> fully unrolled, LDS reads batch-issued.
//   - A/B coeffs read via wave-uniform global pointer (SGPR s_loads).
//   - kgen fused INTO gemm1 launch as blocks [0,64) (independent inputs),
//     so its ~8us latency chain hides under gemm1's MFMA work.
//   - k_prep+k_zero fused into one launch (saves launch overhead).
// ---------------------------------------------------------------------------

#define BSZ   8
#define SEQ   8192
#define CHN   256
#define ORD   64
#define STAPS 512
#define NDD   17            // d-pairs: covers d = 0..33 (taps to 543 >= 511)
#define PREPAD 544          // history prepad (>= 528 needed), 16-aligned
#define XROW  (PREPAD + SEQ) // 8736 elems per (b,c) row of xe^T
#define MTOT  (BSZ * SEQ)   // 65536
#define YELEMS (MTOT * CHN) // 16777216

#define CT     2048         // conv t-tile per block
#define CROWE  3072         // conv LDS row stride (384 chunks)

typedef short s16x8 __attribute__((ext_vector_type(8)));
typedef float f32x4 __attribute__((ext_vector_type(4)));

#define MFMA16(a, b, c) __builtin_amdgcn_mfma_f32_16x16x32_bf16((a), (b), (c), 0, 0, 0)

// async global->LDS 16B: LDS dest = wave-uniform base + lane*16
__device__ __forceinline__ void gll16(const void* g, void* l) {
  __builtin_amdgcn_global_load_lds(
      (const __attribute__((address_space(1))) unsigned int*)g,
      (__attribute__((address_space(3))) unsigned int*)l, 16, 0, 0);
}

// XOR-perm chunk layout: chunk p of (row,h) stored at elems PERMC
#define PERMC(row, h) (((row) * 8 + ((h) ^ ((row) & 7))) * 8)

__device__ __forceinline__ unsigned short f2bf(float f) {
  unsigned u = __float_as_uint(f);
  return (unsigned short)((u + 0x7FFFu + ((u >> 16) & 1u)) >> 16);
}
__device__ __forceinline__ float bf2f(unsigned short h) {
  return __uint_as_float(((unsigned)h) << 16);
}
// tanh-form gelu: x * sigmoid(2*sqrt(2/pi)*(x + 0.044715 x^3)).
// |err| vs exact erf-gelu < ~2e-4, << bf16 noise.
__device__ __forceinline__ float geluf(float x) {
  float x2 = x * x;
  float y = x * __builtin_fmaf(0.0356774081f, x2, 0.7978845608f);
  float e = __builtin_amdgcn_exp2f(-2.8853900818f * y);  // exp(-2y)
  return x * __builtin_amdgcn_rcpf(1.0f + e);
}
__device__ __forceinline__ uint4 packbf8(float4 a, float4 b) {
  uint4 r;
  r.x = (unsigned)f2bf(a.x) | ((unsigned)f2bf(a.y) << 16);
  r.y = (unsigned)f2bf(a.z) | ((unsigned)f2bf(a.w) << 16);
  r.z = (unsigned)f2bf(b.x) | ((unsigned)f2bf(b.y) << 16);
  r.w = (unsigned)f2bf(b.z) | ((unsigned)f2bf(b.w) << 16);
  return r;
}

// -------------------------------------- fused: weights->bf16 + zero prepads
__global__ __launch_bounds__(256) void k_pz(const float* we, const float* wf,
                                            const float* wd, unsigned short* owe,
                                            unsigned short* owf, unsigned short* owd,
                                            unsigned short* xeT, uint4* maxbufs) {
  int bx = blockIdx.x, tid = threadIdx.x;     // grid 1316 = 768 prep + 548 zero
  if (bx < 768) {
    int i = bx * 256 + tid;
    int which = i >> 16, off = i & 65535;
    if (which == 0)      owe[off] = f2bf(we[off]);
    else if (which == 1) owf[off] = f2bf(wf[off]);
    else                 owd[off] = f2bf(wd[off]);
  } else {
    int i = (bx - 768) * 256 + tid;
    uint4 z; z.x = 0; z.y = 0; z.z = 0; z.w = 0;
    if (i < 2048 * 68) {                      // 544 elems/row = 68 x 16B chunks
      int row = i / 68, cc = i % 68;
      *(uint4*)((char*)xeT + (size_t)row * (XROW * 2) + (size_t)cc * 16) = z;
    } else {
      int j = i - 2048 * 68;
      if (j < 1024) maxbufs[j] = z;           // maxxe (8KB) + maxy (8KB)
    }
  }
}

// ---------------- K-gen body: Newton inversion of A(z), fixed-64 unrolled
// loops via zero-padded G (pad [0,64) zeros; unwritten tail pre-zeroed, so
// out-of-range terms contribute exact 0 -- arithmetic identical to bounded
// loops). Per-wave private LDS, one channel per wave.
__device__ __forceinline__ void kgen_body(char* smem, const float* A, const float* Bp,
                                          unsigned short* afr, int blk) {
  int tid = threadIdx.x, lane = tid & 63;
  int wv = __builtin_amdgcn_readfirstlane(tid >> 6);
  int c = blk * 4 + wv;
  float* base = (float*)smem + wv * 1152;     // 4 waves x 4608B = 18432B
  float* Gsp = base;                          // [576], Gsp[64+t] = G[t]
  float* Et  = base + 576;                    // [64]
  float* Kb  = base + 640;                    // [512]
  const float* Ap = A + (size_t)c * ORD;      // a[u] = Ap[u-1], u in [1,64]
  const float* Bb = Bp + (size_t)c * ORD;

  float Au[64];                               // wave-uniform -> SGPRs
#pragma unroll
  for (int u = 0; u < 64; ++u) Au[u] = Ap[u];

#pragma unroll
  for (int k = 0; k < 9; ++k) Gsp[k * 64 + lane] = 0.f;
  if (lane == 0) Gsp[64] = 1.f;
  __syncthreads();

  for (int n = 1; n < STAPS; n <<= 1) {
    // E[n+lane] = sum_u a[u] * G[n+lane-u]; zeros cover u<=lane (G>=n
    // unwritten=0) and u>n+lane (pad)
    float e = 0.f;
#pragma unroll
    for (int u = 1; u <= 64; ++u)
      e += Au[u - 1] * Gsp[64 + n + lane - u];
    Et[lane] = e;
    __syncthreads();
    int nk = (n + 63) >> 6;
    for (int k = 0; k < nk; ++k) {
      int idx = k * 64 + lane;
      float acc = 0.f;
#pragma unroll
      for (int i = 0; i < 64; ++i)
        acc += Et[i] * Gsp[64 + idx - i];
      if (idx < n) Gsp[64 + n + idx] = -acc;
    }
    __syncthreads();
  }

  for (int k = 0; k < 8; ++k) {
    int t = k * 64 + lane;
    float acc = 0.f;
#pragma unroll
    for (int j = 0; j < 64; ++j)
      acc += Bb[j] * Gsp[64 + t - j];
    Kb[t] = acc;
  }
  __syncthreads();

  int m = lane & 15, quad = lane >> 4;
  for (int dd = 0; dd < NDD; ++dd) {
    unsigned short v[8];
#pragma unroll
    for (int j = 0; j < 8; ++j) {
      int k = quad * 8 + j;
      int d = 2 * dd + (k >> 4);
      int p = k & 15;
      int s = 16 * d + m - p;
      float kv = (s >= 0 && s < STAPS) ? Kb[s] : 0.f;
      v[j] = f2bf(kv);
    }
    uint4 pk;
    pk.x = (unsigned)v[0] | ((unsigned)v[1] << 16);
    pk.y = (unsigned)v[2] | ((unsigned)v[3] << 16);
    pk.z = (unsigned)v[4] | ((unsigned)v[5] << 16);
    pk.w = (unsigned)v[6] | ((unsigned)v[7] << 16);
    *(uint4*)(afr + ((size_t)(c * NDD + dd) * 64 + lane) * 8) = pk;
  }
}

// --------------- fused GEMM1 + kgen: blocks [0,64) = kgen, [64,1088) = GEMM1
// GEMM1 (transposed out): xe^T[cout][t] = W_enc x^T + b_enc
// block: 256 cout x 64 t; BK=64; W via global_load_lds, x converted in VGPRs
__global__ __launch_bounds__(256) void k_g1k(const float* A, const float* Bp,
                                             unsigned short* afr,
                                             const float* x, const unsigned short* wb,
                                             const float* benc, unsigned short* xeT,
                                             unsigned int* maxxe) {
  __shared__ __align__(16) char smem[40960];  // union: gemm1 40960B / kgen 18432B
  if (blockIdx.x < 64) {
    kgen_body(smem, A, Bp, afr, blockIdx.x);
    return;
  }
  unsigned short* As = (unsigned short*)smem;           // W tile, perm layout
  unsigned short* Bs = (unsigned short*)(smem + 32768); // x tile, perm layout
  int tid = threadIdx.x, lane = tid & 63, wv = tid >> 6;
  int ln15 = lane & 15, hf = lane >> 4;
  size_t t0 = (size_t)(blockIdx.x - 64) * 64; // 1024 gemm blocks
  int b = (int)(t0 >> 13), tin = (int)(t0 & 8191);
  f32x4 acc[4][4];
#pragma unroll
  for (int i = 0; i < 4; ++i)
#pragma unroll
    for (int j = 0; j < 4; ++j) { acc[i][j][0]=0.f; acc[i][j][1]=0.f; acc[i][j][2]=0.f; acc[i][j][3]=0.f; }

  for (int k0 = 0; k0 < CHN; k0 += 64) {
    __syncthreads();
#pragma unroll
    for (int i = 0; i < 8; ++i) {
      int p = 512 * wv + 64 * i + lane;
      int row = p >> 3, h = (p & 7) ^ (row & 7);
      gll16(wb + (size_t)row * CHN + k0 + h * 8, &As[(512 * wv + 64 * i) * 8]);
    }
    {  // x: 64x64 fp32->bf16, 2 chunks/thread
      int row = tid >> 2, hb = (tid & 3) * 2;
      const float* src = x + (t0 + row) * CHN + k0 + hb * 8;
      float4 f0 = *(const float4*)src;
      float4 f1 = *(const float4*)(src + 4);
      float4 f2 = *(const float4*)(src + 8);
      float4 f3 = *(const float4*)(src + 12);
      *(uint4*)&Bs[PERMC(row, hb)]     = packbf8(f0, f1);
      *(uint4*)&Bs[PERMC(row, hb + 1)] = packbf8(f2, f3);
    }
    __syncthreads();
#pragma unroll
    for (int ks = 0; ks < 2; ++ks) {
      s16x8 af[4], bfr[4];
#pragma unroll
      for (int mt = 0; mt < 4; ++mt) {
        int row = 64 * wv + 16 * mt + ln15;
        af[mt] = *(const s16x8*)&As[PERMC(row, ks * 4 + hf)];
      }
#pragma unroll
      for (int nt = 0; nt < 4; ++nt) {
        int row = 16 * nt + ln15;
        bfr[nt] = *(const s16x8*)&Bs[PERMC(row, ks * 4 + hf)];
      }
#pragma unroll
      for (int mt = 0; mt < 4; ++mt)
#pragma unroll
        for (int nt = 0; nt < 4; ++nt)
          acc[mt][nt] = MFMA16(af[mt], bfr[nt], acc[mt][nt]);
    }
  }
  // epilogue: D[m=cout][n=t]; col=lane&15=t, row=quad*4+r
  int quad = hf;
#pragma unroll
  for (int mt = 0; mt < 4; ++mt) {
#pragma unroll
    for (int r = 0; r < 4; ++r) {
      int row = 64 * wv + 16 * mt + 4 * quad + r;
      float bias = benc[row];
      float mv = 0.f;
#pragma unroll
      for (int nt = 0; nt < 4; ++nt) {
        float v = acc[mt][nt][r] + bias;
        int t = tin + 16 * nt + ln15;
        xeT[(size_t)(b * CHN + row) * XROW + PREPAD + t] = f2bf(v);
        mv = fmaxf(mv, fabsf(v));
      }
      mv = fmaxf(mv, __shfl_xor(mv, 1)); mv = fmaxf(mv, __shfl_xor(mv, 2));
      mv = fmaxf(mv, __shfl_xor(mv, 4)); mv = fmaxf(mv, __shfl_xor(mv, 8));
      if (ln15 == 0) atomicMax(&maxxe[b * CHN + row], __float_as_uint(mv));
    }
  }
}

// ------------- conv: y1[t][c] = gelu(FIR(xe) + h0*xe)
// block = 4 ch x 2048 t; wave owns 1 channel; A-frags in VGPRs.
// Swizzled LDS addresses slide in registers (rotate-8 + (a+512)^64).
__global__ __launch_bounds__(256) void k_conv(const unsigned short* xeT,
                                              const unsigned short* afr,
                                              unsigned short* y1, const float* h0p) {
  __shared__ __align__(16) unsigned short xet[4 * CROWE]; // 4 rows x 384 chunks
  __shared__ __align__(16) unsigned short bnc[4 * CT];    // transpose bounce
  int tid = threadIdx.x, lane = tid & 63, wv = tid >> 6;
  int idx = blockIdx.x;                          // grid 2048 = 8b x 64cg x 4tg
  int tg = idx & 3, cg = (idx >> 2) & 63, b = idx >> 8;
  int c0 = cg * 4, t0 = tg * CT;
  int c = c0 + wv;

  // a-frags into registers (17 x 16B coalesced loads)
  s16x8 afrg[NDD];
  {
    const unsigned short* ap = afr + (size_t)c * (NDD * 512) + (size_t)lane * 8;
#pragma unroll
    for (int dd = 0; dd < NDD; ++dd)
      afrg[dd] = *(const s16x8*)(ap + (size_t)dd * 512);
  }
  // stage own channel's row [t0-544, t0+2048+..) via global_load_lds;
  // LDS slot s holds global chunk s^((s>>3)&7) (involution), so read-side
  // swizzle sw = cc^((cc>>3)&7) finds chunk cc.
  {
    int lp = lane ^ ((lane >> 3) & 7);
    const unsigned short* gbase = xeT + (size_t)(b * CHN + c) * XROW + t0;
    unsigned short* lbase = &xet[wv * CROWE];
#pragma unroll
    for (int k = 0; k < 6; ++k)
      gll16(gbase + (size_t)(64 * k + lp) * 8, &lbase[k * 64 * 8]);
  }
  float h0 = h0p[0];

  int n = lane & 15, quad = lane >> 4;
  int qc = quad - ((quad >> 1) << 2);            // 0,1,-2,-1
  const char* xb = (const char*)&xet[wv * CROWE];

  // sliding swizzled byte addresses: ad[dd](s) = sw(cb0 + 32s - 4dd)*16.
  // Slide: ad(s+1,dd>=8) = ad(s,dd-8); ad(s+1,dd<8) = (ad(s,dd)+512)^64.
  int ad[NDD];
  {
    int cb0 = 2 * n + qc + 68;
#pragma unroll
    for (int dd = 0; dd < NDD; ++dd) {
      int cc = cb0 - 4 * dd;
      ad[dd] = (cc ^ ((cc >> 3) & 7)) * 16;
    }
  }
  // epilogue xv address: chunk 68 + 2n + (quad>>1), byte off 8*(quad&1)
  int ead;
  {
    int ch = 68 + 2 * n + (quad >> 1);
    ead = (ch ^ ((ch >> 3) & 7)) * 16 + 8 * (quad & 1);
  }
  __syncthreads();

#pragma unroll 1
  for (int s = 0; s < 8; ++s) {
    f32x4 a0, a1;
    a0[0]=0.f; a0[1]=0.f; a0[2]=0.f; a0[3]=0.f;
    a1[0]=0.f; a1[1]=0.f; a1[2]=0.f; a1[3]=0.f;
#pragma unroll
    for (int dd = 0; dd < 16; dd += 2) {
      a0 = MFMA16(afrg[dd],     *(const s16x8*)(xb + ad[dd]),     a0);
      a1 = MFMA16(afrg[dd + 1], *(const s16x8*)(xb + ad[dd + 1]), a1);
    }
    a0 = MFMA16(afrg[16], *(const s16x8*)(xb + ad[16]), a0);
    // epilogue: tl = 256s + 16n + 4q + r; xv for 4 r's = one b64 read
    uint2 xvp = *(const uint2*)(xb + ead);
    unsigned short o[4];
#pragma unroll
    for (int r = 0; r < 4; ++r) {
      float xv = bf2f(((const unsigned short*)&xvp)[r]);
      float v = (a0[r] + a1[r]) + h0 * xv;
      o[r] = f2bf(geluf(v));
    }
    uint2 pw;
    pw.x = (unsigned)o[0] | ((unsigned)o[1] << 16);
    pw.y = (unsigned)o[2] | ((unsigned)o[3] << 16);
    *(uint2*)&bnc[wv * CT + 256 * s + 16 * n + 4 * quad] = pw;
    // slide addresses to s+1 (rotate high<-low, then bump low 8)
#pragma unroll
    for (int dd = 16; dd >= 8; --dd) ad[dd] = ad[dd - 8];
#pragma unroll
    for (int dd = 0; dd < 8; ++dd) ad[dd] = (ad[dd] + 512) ^ 64;
    ead = (ead + 512) ^ 64;
  }
  __syncthreads();
  // store: 4 ch per t as uint2, 8 rounds
  {
    const size_t obase = (size_t)(b * SEQ + t0) * CHN + c0;
#pragma unroll
    for (int s = 0; s < 8; ++s) {
      int tl = 256 * s + tid;
      uint2 pk;
      pk.x = (unsigned)bnc[tl] | ((unsigned)bnc[CT + tl] << 16);
      pk.y = (unsigned)bnc[2 * CT + tl] | ((unsigned)bnc[3 * CT + tl] << 16);
      *(uint2*)(y1 + obase + (size_t)tl * CHN) = pk;
    }
  }
}

// ------ GEMM2: y2n = LN(gelu(y1 W_fc^T + b_fc) + xe)*gamma+beta, in-place y1
// block: 64 t x 256 cout; BK=64; full global_load_lds staging
__global__ __launch_bounds__(256) void k_gemm2(const unsigned short* y1,
                                               const unsigned short* wb, const float* bfc,
                                               const unsigned short* xeT, const float* gam,
                                               const float* bet, unsigned short* y2n) {
  __shared__ __align__(16) unsigned short Ws[256 * 64];
  __shared__ __align__(16) unsigned short Asb[64 * 64];
  __shared__ float pl[64][2][2];
  int tid = threadIdx.x, lane = tid & 63, wv = tid >> 6;
  int ln15 = lane & 15, hf = lane >> 4, quad = hf;
  size_t M0 = (size_t)blockIdx.x * 64;           // grid 1024
  int b = (int)(M0 >> 13), tin = (int)(M0 & 8191);
  int mh = wv & 1, nh = wv >> 1;
  f32x4 acc[2][8];
#pragma unroll
  for (int i = 0; i < 2; ++i)
#pragma unroll
    for (int j = 0; j < 8; ++j) { acc[i][j][0]=0.f; acc[i][j][1]=0.f; acc[i][j][2]=0.f; acc[i][j][3]=0.f; }

  for (int k0 = 0; k0 < CHN; k0 += 64) {
    __syncthreads();
#pragma unroll
    for (int i = 0; i < 8; ++i) {               // W: 2048 chunks
      int p = 512 * wv + 64 * i + lane;
      int row = p >> 3, h = (p & 7) ^ (row & 7);
      gll16(wb + (size_t)row * CHN + k0 + h * 8, &Ws[(512 * wv + 64 * i) * 8]);
    }
#pragma unroll
    for (int i = 0; i < 2; ++i) {               // A: 512 chunks
      int p = 128 * wv + 64 * i + lane;
      int row = p >> 3, h = (p & 7) ^ (row & 7);
      gll16(y1 + (M0 + row) * CHN + k0 + h * 8, &Asb[(128 * wv + 64 * i) * 8]);
    }
    __syncthreads();
#pragma unroll
    for (int ks = 0; ks < 2; ++ks) {
      s16x8 af[2], bfr[8];
#pragma unroll
      for (int mt = 0; mt < 2; ++mt) {
        int row = 32 * mh + 16 * mt + ln15;
        af[mt] = *(const s16x8*)&Asb[PERMC(row, ks * 4 + hf)];
      }
#pragma unroll
      for (int nt = 0; nt < 8; ++nt) {
        int row = 128 * nh + 16 * nt + ln15;
        bfr[nt] = *(const s16x8*)&Ws[PERMC(row, ks * 4 + hf)];
      }
#pragma unroll
      for (int mt = 0; mt < 2; ++mt)
#pragma unroll
        for (int nt = 0; nt < 8; ++nt)
          acc[mt][nt] = MFMA16(af[mt], bfr[nt], acc[mt][nt]);
    }
  }
  float g8[8], be8[8], bf8[8];
#pragma unroll
  for (int nt = 0; nt < 8; ++nt) {
    int col = 128 * nh + 16 * nt + ln15;
    g8[nt] = gam[col]; be8[nt] = bet[col]; bf8[nt] = bfc[col];
  }
#pragma unroll
  for (int mt = 0; mt < 2; ++mt) {
    int mlb = 32 * mh + 16 * mt + 4 * quad;
    uint2 xv2[8];
#pragma unroll
    for (int nt = 0; nt < 8; ++nt) {            // xe skip: 4 consecutive t per lane
      int col = 128 * nh + 16 * nt + ln15;
      xv2[nt] = *(const uint2*)(xeT + (size_t)(b * CHN + col) * XROW + PREPAD + tin + mlb);
    }
#pragma unroll
    for (int r = 0; r < 4; ++r) {
      int ml = mlb + r;
      float s1 = 0.f, s2 = 0.f;
#pragma unroll
      for (int nt = 0; nt < 8; ++nt) {
        float t2 = acc[mt][nt][r] + bf8[nt];
        float xv = bf2f(((const unsigned short*)&xv2[nt])[r]);
        float y2 = geluf(t2) + xv;
        acc[mt][nt][r] = y2;
        s1 += y2; s2 += y2 * y2;
      }
      s1 += __shfl_xor(s1, 1); s2 += __shfl_xor(s2, 1);
      s1 += __shfl_xor(s1, 2); s2 += __shfl_xor(s2, 2);
      s1 += __shfl_xor(s1, 4); s2 += __shfl_xor(s2, 4);
      s1 += __shfl_xor(s1, 8); s2 += __shfl_xor(s2, 8);
      if (ln15 == 0) { pl[ml][nh][0] = s1; pl[ml][nh][1] = s2; }
    }
  }
  __syncthreads();
#pragma unroll
  for (int mt = 0; mt < 2; ++mt) {
#pragma unroll
    for (int r = 0; r < 4; ++r) {
      int ml = 32 * mh + 16 * mt + 4 * quad + r;
      float s1 = pl[ml][0][0] + pl[ml][1][0];
      float s2 = pl[ml][0][1] + pl[ml][1][1];
      float mu = s1 * (1.f / 256.f);
      float var = s2 * (1.f / 256.f) - mu * mu;
      float ri = rsqrtf(var + 1e-5f);
#pragma unroll
      for (int nt = 0; nt < 8; ++nt) {
        int col = 128 * nh + 16 * nt + ln15;
        float yn = (acc[mt][nt][r] - mu) * ri * g8[nt] + be8[nt];
        y2n[(M0 + ml) * CHN + col] = f2bf(yn);
      }
    }
  }
}

// ------------------- GEMM3: y = y2n W_dec^T + b_dec (fp32 out) + maxy atomics
__global__ __launch_bounds__(256) void k_gemm3(const unsigned short* y2n,
                                               const unsigned short* wb, const float* bd,
                                               float* yout, unsigned int* maxy) {
  __shared__ __align__(16) unsigned short Ws[256 * 64];
  __shared__ __align__(16) unsigned short Asb[64 * 64];
  int tid = threadIdx.x, lane = tid & 63, wv = tid >> 6;
  int ln15 = lane & 15, hf = lane >> 4, quad = hf;
  size_t M0 = (size_t)blockIdx.x * 64;           // grid 1024
  int b = (int)(M0 >> 13);
  int mh = wv & 1, nh = wv >> 1;
  f32x4 acc[2][8];
#pragma unroll
  for (int i = 0; i < 2; ++i)
#pragma unroll
    for (int j = 0; j < 8; ++j) { acc[i][j][0]=0.f; acc[i][j][1]=0.f; acc[i][j][2]=0.f; acc[i][j][3]=0.f; }

  for (int k0 = 0; k0 < CHN; k0 += 64) {
    __syncthreads();
#pragma unroll
    for (int i = 0; i < 8; ++i) {               // W: 2048 chunks
      int p = 512 * wv + 64 * i + lane;
      int row = p >> 3, h = (p & 7) ^ (row & 7);
      gll16(wb + (size_t)row * CHN + k0 + h * 8, &Ws[(512 * wv + 64 * i) * 8]);
    }
#pragma unroll
    for (int i = 0; i < 2; ++i) {               // A: 512 chunks
      int p = 128 * wv + 64 * i + lane;
      int row = p >> 3, h = (p & 7) ^ (row & 7);
      gll16(y2n + (M0 + row) * CHN + k0 + h * 8, &Asb[(128 * wv + 64 * i) * 8]);
    }
    __syncthreads();
#pragma unroll
    for (int ks = 0; ks < 2; ++ks) {
      s16x8 af[2], bfr[8];
#pragma unroll
      for (int mt = 0; mt < 2; ++mt) {
        int row = 32 * mh + 16 * mt + ln15;
        af[mt] = *(const s16x8*)&Asb[PERMC(row, ks * 4 + hf)];
      }
#pragma unroll
      for (int nt = 0; nt < 8; ++nt) {
        int row = 128 * nh + 16 * nt + ln15;
        bfr[nt] = *(const s16x8*)&Ws[PERMC(row, ks * 4 + hf)];
      }
#pragma unroll
      for (int mt = 0; mt < 2; ++mt)
#pragma unroll
        for (int nt = 0; nt < 8; ++nt)
          acc[mt][nt] = MFMA16(af[mt], bfr[nt], acc[mt][nt]);
    }
  }
  float bd8[8];
#pragma unroll
  for (int nt = 0; nt < 8; ++nt) bd8[nt] = bd[128 * nh + 16 * nt + ln15];
#pragma unroll
  for (int mt = 0; mt < 2; ++mt)
#pragma unroll
    for (int r = 0; r < 4; ++r) {
      int ml = 32 * mh + 16 * mt + 4 * quad + r;
#pragma unroll
      for (int nt = 0; nt < 8; ++nt) {
        int col = 128 * nh + 16 * nt + ln15;
        float v = acc[mt][nt][r] + bd8[nt];
        acc[mt][nt][r] = v;
        yout[(M0 + ml) * CHN + col] = v;
      }
    }
#pragma unroll
  for (int nt = 0; nt < 8; ++nt) {
    int col = 128 * nh + 16 * nt + ln15;
    float mv = 0.f;
#pragma unroll
    for (int mt = 0; mt < 2; ++mt)
#pragma unroll
      for (int r = 0; r < 4; ++r) mv = fmaxf(mv, fabsf(acc[mt][nt][r]));
    mv = fmaxf(mv, __shfl_xor(mv, 16));
    mv = fmaxf(mv, __shfl_xor(mv, 32));
    if (quad == 0) atomicMax(&maxy[b * CHN + col], __float_as_uint(mv));
  }
}

// ------------------------------------------------------------ h = my/(mx+eps)
__global__ __launch_bounds__(256) void k_hfin(const unsigned int* maxxe,
                                              const unsigned int* maxy, float* hout) {
  int i = blockIdx.x * 256 + threadIdx.x;        // grid 8
  if (i < BSZ * CHN) {
    float mx = __uint_as_float(maxxe[i]);
    float my = __uint_as_float(maxy[i]);
    hout[i] = my / (mx + 1e-6f);
  }
}

// ---------------------------------------------------------------------------
extern "C" void kernel_launch(void* const* d_in, const int* in_sizes, int n_in,
                              void* d_out, int out_size, void* d_ws, size_t ws_size,
                              hipStream_t stream) {
  const float* x   = (const float*)d_in[0];
  const float* A   = (const float*)d_in[1];
  const float* Bp  = (const float*)d_in[2];
  const float* h0  = (const float*)d_in[3];
  const float* We  = (const float*)d_in[4];
  const float* be  = (const float*)d_in[5];
  const float* Wf  = (const float*)d_in[6];
  const float* bfc = (const float*)d_in[7];
  const float* gam = (const float*)d_in[8];
  const float* bet = (const float*)d_in[9];
  const float* Wd  = (const float*)d_in[10];
  const float* bd  = (const float*)d_in[11];

  char* ws = (char*)d_ws;
  unsigned short* y1  = (unsigned short*)(ws + 0);          // 33554432 B
  unsigned short* afr = (unsigned short*)(ws + 33554432);   //  4456448 B
  unsigned short* web = (unsigned short*)(ws + 38010880);   //   131072 B
  unsigned short* wfb = (unsigned short*)(ws + 38141952);
  unsigned short* wdb = (unsigned short*)(ws + 38273024);
  unsigned int*  maxxe = (unsigned int*)(ws + 38404096);    //     8192 B
  unsigned int*  maxy  = (unsigned int*)(ws + 38412288);    //     8192 B

  unsigned short* xeT = (unsigned short*)d_out;             // scratch: 35.8 MB
  float* yout = (float*)d_out;
  float* hout = yout + YELEMS;

  k_pz<<<1316, 256, 0, stream>>>(We, Wf, Wd, web, wfb, wdb, xeT, (uint4*)maxxe);
  k_g1k<<<1088, 256, 0, stream>>>(A, Bp, afr, x, web, be, xeT, maxxe);
  k_conv<<<2048, 256, 0, stream>>>(xeT, afr, y1, h0);
  k_gemm2<<<1024, 256, 0, stream>>>(y1, wfb, bfc, xeT, gam, bet, y1);
  k_gemm3<<<1024, 256, 0, stream>>>(y1, wdb, bd, yout, maxy);
  k_hfin<<<8, 256, 0, stream>>>(maxxe, maxy, hout);
}